// Round 15
// baseline (28.466 us; speedup 1.0000x reference)
//
#include <hip/hip_runtime.h>

// attention_pooling: out[b,:] = softmax(feats@Wi over valid rows)-weighted
// mean of feats, then @Wj + bj.  softmax weights sum to 1, so
// out = (Σ_n w_n feats_n / Σ_n w_n) @ Wj + bj — no B×N×D×HID GEMM needed.
//
// R15 = R11 structure with a CORRECT consumer tail.
//  - R14 tripwire lesson: plain cached loads of cross-XCD-produced partials
//    can hit STALE lines (0xAA poison) in the consumer XCD's L2 — agent
//    write-through stores update the coherence point but don't invalidate
//    remote L2 copies. ALL partial reads must be agent-scope atomic loads.
//  - Tail kept fast by BATCHING: 4 chunks (8 atomic loads) into independent
//    temporaries per summation — one waitcnt per batch, not per load
//    (R6-R9's serial tail was acc += atomic_load forcing per-load waits).
//  - Consumers SELF-CLEAR their graph's flags after the reduce: next call
//    always waits properly (no stale-MAGIC shortcut), no memset dispatch.
//  - R10: observe ALL flags before reading ANY partial. R4: __threadfence
//    banned. R8: ticket atomics banned. R5: no min-waves launch cap.

#define NDIM 256        // NODE_DIM + HID_DIM
#define HID 128
#define NMAX 4096
#define ROWS_PER_BLK 160
#define NCHUNK 26                      // ceil(4096/160)
#define PSTRIDE 260                    // 256 acc + 1 lsum
#define FLAG_MAGIC 0x5EED5EEDu

#define ALOAD(p)     __hip_atomic_load((p),  __ATOMIC_RELAXED, __HIP_MEMORY_SCOPE_AGENT)
#define ASTORE(p, v) __hip_atomic_store((p), (v), __ATOMIC_RELAXED, __HIP_MEMORY_SCOPE_AGENT)

__global__ __launch_bounds__(512) void pool_fused(
    const float* __restrict__ feats, const int* __restrict__ counts,
    const float* __restrict__ Wi, const float* __restrict__ bi,
    const float* __restrict__ Wj, const float* __restrict__ bj,
    unsigned int* __restrict__ flags, float* __restrict__ part_g,
    float* __restrict__ out)
{
    const int b     = blockIdx.y;
    const int count = counts[b];
    const int tid   = threadIdx.x;
    const int nch   = (count + ROWS_PER_BLK - 1) / ROWS_PER_BLK;

    __shared__ float lds_acc[8][NDIM];
    __shared__ float lds_l[8];
    __shared__ float red[2][NDIM];
    __shared__ float redl[2];
    __shared__ float pooled[NDIM];
    __shared__ float tmp[4][HID];

    if (blockIdx.x < NCHUNK) {
        // ---------------- producer: one 160-row chunk ----------------
        const int row0 = blockIdx.x * ROWS_PER_BLK;
        if (row0 >= count) return;                    // masked chunk: never read
        const int row_end = min(row0 + ROWS_PER_BLK, count);

        const int lane = tid & 63;
        const int wv   = tid >> 6;       // 0..7
        const int g    = lane >> 4;      // 0..3: row within quad
        const int q    = lane & 15;      // col-group owner

        const float4* Wi4 = reinterpret_cast<const float4*>(Wi);
        const float4 wi0 = Wi4[q], wi1 = Wi4[16 + q], wi2 = Wi4[32 + q], wi3 = Wi4[48 + q];
        const float  fbi = bi[0];

        const float* fb = feats + (size_t)b * NMAX * NDIM;

        float4 a0 = {0,0,0,0}, a1 = {0,0,0,0}, a2 = {0,0,0,0}, a3 = {0,0,0,0};
        float lsum = 0.f;

        const int wbase = row0 + wv * 20;             // wave owns 20 rows
        #pragma unroll
        for (int it = 0; it < 5; ++it) {
            const int r = wbase + it * 4 + g;
            const bool valid = (r < row_end);
            float4 f0 = {0,0,0,0}, f1 = {0,0,0,0}, f2 = {0,0,0,0}, f3 = {0,0,0,0};
            if (valid) {
                const float4* rp = reinterpret_cast<const float4*>(fb + (size_t)r * NDIM);
                f0 = rp[q]; f1 = rp[16 + q]; f2 = rp[32 + q]; f3 = rp[48 + q];
            }
            float sp = f0.x*wi0.x + f0.y*wi0.y + f0.z*wi0.z + f0.w*wi0.w
                     + f1.x*wi1.x + f1.y*wi1.y + f1.z*wi1.z + f1.w*wi1.w
                     + f2.x*wi2.x + f2.y*wi2.y + f2.z*wi2.z + f2.w*wi2.w
                     + f3.x*wi3.x + f3.y*wi3.y + f3.z*wi3.z + f3.w*wi3.w;
            sp += __shfl_xor(sp, 1, 64);
            sp += __shfl_xor(sp, 2, 64);
            sp += __shfl_xor(sp, 4, 64);
            sp += __shfl_xor(sp, 8, 64);
            const float w = valid ? __expf(sp + fbi) : 0.f;
            lsum += w;
            a0.x += w*f0.x; a0.y += w*f0.y; a0.z += w*f0.z; a0.w += w*f0.w;
            a1.x += w*f1.x; a1.y += w*f1.y; a1.z += w*f1.z; a1.w += w*f1.w;
            a2.x += w*f2.x; a2.y += w*f2.y; a2.z += w*f2.z; a2.w += w*f2.w;
            a3.x += w*f3.x; a3.y += w*f3.y; a3.z += w*f3.z; a3.w += w*f3.w;
        }

        #define COMB(x) x += __shfl_xor(x, 16, 64); x += __shfl_xor(x, 32, 64)
        COMB(a0.x); COMB(a0.y); COMB(a0.z); COMB(a0.w);
        COMB(a1.x); COMB(a1.y); COMB(a1.z); COMB(a1.w);
        COMB(a2.x); COMB(a2.y); COMB(a2.z); COMB(a2.w);
        COMB(a3.x); COMB(a3.y); COMB(a3.z); COMB(a3.w);
        COMB(lsum);
        #undef COMB

        if (g == 0) {                                 // lane < 16: one writer per col-set
            float* dst = &lds_acc[wv][0];
            *reinterpret_cast<float4*>(&dst[q*4      ]) = a0;
            *reinterpret_cast<float4*>(&dst[q*4 +  64]) = a1;
            *reinterpret_cast<float4*>(&dst[q*4 + 128]) = a2;
            *reinterpret_cast<float4*>(&dst[q*4 + 192]) = a3;
            if (q == 0) lds_l[wv] = lsum;
        }
        __syncthreads();

        // partial store: agent-scope relaxed (write-through, no cache ops)
        float* part = part_g + (size_t)(b * NCHUNK + blockIdx.x) * PSTRIDE;
        if (tid < NDIM) {
            float v = 0.f;
            #pragma unroll
            for (int k = 0; k < 8; ++k) v += lds_acc[k][tid];
            ASTORE(&part[tid], v);
        } else if (tid == NDIM) {
            float v = 0.f;
            #pragma unroll
            for (int k = 0; k < 8; ++k) v += lds_l[k];
            ASTORE(&part[NDIM], v);
        }
        __syncthreads();   // drains vmcnt(0): partials at coherence point
        if (tid == 0)
            ASTORE(&flags[b * NCHUNK + blockIdx.x], FLAG_MAGIC);
        return;
    }

    // ---------------- consumer: blockIdx.x == NCHUNK, one per graph ----------------
    // Phase 1: observe ALL flags (lane-parallel polling).
    if (tid < 64) {
        for (int c = (int)tid; c < nch; c += 64)
            while (ALOAD(&flags[b * NCHUNK + c]) != FLAG_MAGIC)
                __builtin_amdgcn_s_sleep(2);
    }
    __syncthreads();                  // all 512 threads see: every flag set
    asm volatile("" ::: "memory");    // no hoisting the reduce loads above polls

    // Phase 2: reduce with AGENT-SCOPE ATOMIC loads (coherence point — plain
    // cached loads can hit stale poison lines in this XCD's L2: R14 bug).
    // Batched 4 chunks / 8 loads per summation to keep loads in flight.
    const int t    = tid & (NDIM - 1);
    const int half = tid >> 8;                    // 0/1
    float acc = 0.f, l = 0.f;
    {
        const size_t base = (size_t)b * NCHUNK;
        int c = half;
        for (; c + 6 < nch; c += 8) {
            const float* p0 = part_g + (base + c    ) * PSTRIDE;
            const float* p1 = part_g + (base + c + 2) * PSTRIDE;
            const float* p2 = part_g + (base + c + 4) * PSTRIDE;
            const float* p3 = part_g + (base + c + 6) * PSTRIDE;
            float v0 = ALOAD(&p0[t]);
            float v1 = ALOAD(&p1[t]);
            float v2 = ALOAD(&p2[t]);
            float v3 = ALOAD(&p3[t]);
            float w0 = ALOAD(&p0[NDIM]);
            float w1 = ALOAD(&p1[NDIM]);
            float w2 = ALOAD(&p2[NDIM]);
            float w3 = ALOAD(&p3[NDIM]);
            acc += (v0 + v1) + (v2 + v3);
            l   += (w0 + w1) + (w2 + w3);
        }
        for (; c < nch; c += 2) {
            const float* p = part_g + (base + c) * PSTRIDE;
            float v0 = ALOAD(&p[t]);
            float w0 = ALOAD(&p[NDIM]);
            acc += v0;
            l   += w0;
        }
    }
    red[half][t] = acc;
    if (t == 0) redl[half] = l;
    __syncthreads();                  // all partial reads complete

    // Self-clear this graph's flags so the NEXT call waits properly
    // (removes the stale-MAGIC shortcut that made replays racy).
    if (tid < nch)
        ASTORE(&flags[b * NCHUNK + tid], 0u);

    if (tid < NDIM)
        pooled[tid] = (red[0][tid] + red[1][tid]) / (redl[0] + redl[1]);
    __syncthreads();

    const int j  = tid & (HID - 1);
    const int ks = (tid >> 7) * 64;               // K-quarter
    float s = 0.f;
    #pragma unroll 16
    for (int k = 0; k < 64; ++k)
        s += pooled[ks + k] * Wj[(ks + k) * HID + j];   // Wj coalesced over j
    tmp[tid >> 7][j] = s;
    __syncthreads();
    if (tid < HID)
        out[b * HID + tid] = tmp[0][tid] + tmp[1][tid] + tmp[2][tid]
                           + tmp[3][tid] + bj[tid];
}

extern "C" void kernel_launch(void* const* d_in, const int* in_sizes, int n_in,
                              void* d_out, int out_size, void* d_ws, size_t ws_size,
                              hipStream_t stream) {
    const float* feats  = (const float*)d_in[0];
    const int*   counts = (const int*)  d_in[1];
    const float* Wi     = (const float*)d_in[2];
    const float* bi     = (const float*)d_in[3];
    const float* Wj     = (const float*)d_in[4];
    const float* bj     = (const float*)d_in[5];
    float* out = (float*)d_out;

    const int B = in_sizes[1];                    // 64

    unsigned int* flags  = (unsigned int*)d_ws;              // [B*NCHUNK]
    float*        part_g = (float*)((char*)d_ws + 16384);    // [B][NCHUNK][PSTRIDE]

    dim3 g1(NCHUNK + 1, B);
    pool_fused<<<g1, 512, 0, stream>>>(feats, counts, Wi, bi, Wj, bj,
                                       flags, part_g, out);
}